// Round 4
// baseline (2554.424 us; speedup 1.0000x reference)
//
#include <hip/hip_runtime.h>

#define EMB 32
#define BSHIFT 7
#define RPB 128            // rows per bucket = 1 << BSHIFT
#define NBP 2048           // max buckets supported
#define TILE 4096
#define PT_THREADS 512
#define PT_ITEMS 8         // TILE / PT_THREADS
#define COLMASK 0x3FFFF    // 18 bits for col (n <= 262144)

// ---------------- bucket build ----------------

// Global bucket histogram (bucket = row >> BSHIFT), LDS-aggregated.
__global__ __launch_bounds__(512) void bucket_hist_kernel(
        const int* __restrict__ rows, int nnz, int* __restrict__ bhist, int nb) {
    __shared__ int h[NBP];
    const int t = threadIdx.x;
    for (int e = t; e < NBP; e += 512) h[e] = 0;
    __syncthreads();
    int stride = gridDim.x * blockDim.x;
    for (int i = blockIdx.x * blockDim.x + t; i < nnz; i += stride)
        atomicAdd(&h[rows[i] >> BSHIFT], 1);
    __syncthreads();
    for (int e = t; e < nb; e += 512)
        if (h[e] > 0) atomicAdd(&bhist[e], h[e]);
}

// Exclusive scan of bucket hist (nb <= NBP), 1 block, 512 thr, 4 elems/thr.
__global__ __launch_bounds__(512) void bucket_scan_kernel(
        const int* __restrict__ bhist, int nb, int nnz,
        int* __restrict__ base, int* __restrict__ cursor) {
    __shared__ int partial[512];
    const int t = threadIdx.x;
    const int e0 = t * 4;
    int a0 = (e0 + 0 < nb) ? bhist[e0 + 0] : 0;
    int a1 = (e0 + 1 < nb) ? bhist[e0 + 1] : 0;
    int a2 = (e0 + 2 < nb) ? bhist[e0 + 2] : 0;
    int a3 = (e0 + 3 < nb) ? bhist[e0 + 3] : 0;
    int s = a0 + a1 + a2 + a3;
    partial[t] = s;
    __syncthreads();
    for (int off = 1; off < 512; off <<= 1) {
        int add = (t >= off) ? partial[t - off] : 0;
        __syncthreads();
        partial[t] += add;
        __syncthreads();
    }
    int run = partial[t] - s;  // exclusive chunk base
    if (e0 + 0 < nb) { base[e0 + 0] = run; cursor[e0 + 0] = run; } run += a0;
    if (e0 + 1 < nb) { base[e0 + 1] = run; cursor[e0 + 1] = run; } run += a1;
    if (e0 + 2 < nb) { base[e0 + 2] = run; cursor[e0 + 2] = run; } run += a2;
    if (e0 + 3 < nb) { base[e0 + 3] = run; cursor[e0 + 3] = run; } run += a3;
    if (t == 0) base[nb] = nnz;
}

// Tile-wise partition into bucket-contiguous packed pairs, LDS reorder for
// near-coalesced writes. Output: pairs[i] = (val_bits, col | lrow<<18).
__global__ __launch_bounds__(PT_THREADS) void partition_kernel(
        const float* __restrict__ vals, const int* __restrict__ rows,
        const int* __restrict__ cols, int nnz, int* __restrict__ cursor,
        int2* __restrict__ pairs) {
    __shared__ int h[NBP];          // hist -> running rank cursor
    __shared__ int delta[NBP];
    __shared__ int partial[512];
    __shared__ float s_val[TILE];
    __shared__ int s_pack[TILE];
    __shared__ unsigned short s_bkt[TILE];
    const int t = threadIdx.x;
    const int tile_start = blockIdx.x * TILE;
    const int tile_cnt = min(TILE, nnz - tile_start);
    for (int e = t; e < NBP; e += 512) h[e] = 0;
    __syncthreads();
    float v[PT_ITEMS];
    int pk[PT_ITEMS], b[PT_ITEMS];
    #pragma unroll
    for (int k = 0; k < PT_ITEMS; ++k) {
        int i = tile_start + t + k * PT_THREADS;
        if (i < nnz) {
            int r = rows[i];
            v[k] = vals[i];
            pk[k] = cols[i] | ((r & (RPB - 1)) << 18);
            b[k] = r >> BSHIFT;
            atomicAdd(&h[b[k]], 1);
        } else {
            b[k] = -1;
        }
    }
    __syncthreads();
    // chunked exclusive scan over h[0..NBP)
    const int e0 = t * 4;
    int a0 = h[e0], a1 = h[e0 + 1], a2 = h[e0 + 2], a3 = h[e0 + 3];
    int s = a0 + a1 + a2 + a3;
    partial[t] = s;
    __syncthreads();
    for (int off = 1; off < 512; off <<= 1) {
        int add = (t >= off) ? partial[t - off] : 0;
        __syncthreads();
        partial[t] += add;
        __syncthreads();
    }
    int run = partial[t] - s;
    // per-element: reserve global range, set delta, convert h -> rank cursor
    int aa[4] = {a0, a1, a2, a3};
    #pragma unroll
    for (int k = 0; k < 4; ++k) {
        int e = e0 + k;
        int own = aa[k];
        if (own > 0) {
            int rsv = atomicAdd(&cursor[e], own);
            delta[e] = rsv - run;
        }
        h[e] = run;
        run += own;
    }
    __syncthreads();
    // LDS reorder into bucket-sorted order
    #pragma unroll
    for (int k = 0; k < PT_ITEMS; ++k) {
        if (b[k] >= 0) {
            int rank = atomicAdd(&h[b[k]], 1);
            s_val[rank] = v[k];
            s_pack[rank] = pk[k];
            s_bkt[rank] = (unsigned short)b[k];
        }
    }
    __syncthreads();
    // copy out: consecutive sorted items -> consecutive global slots
    for (int i = t; i < tile_cnt; i += PT_THREADS) {
        int bb = s_bkt[i];
        pairs[delta[bb] + i] = make_int2(__float_as_int(s_val[i]), s_pack[i]);
    }
}

// ---------------- misc ----------------

__global__ void softmax4_kernel(const float* __restrict__ alpha, float* __restrict__ coefs) {
    if (threadIdx.x == 0 && blockIdx.x == 0) {
        float m = fmaxf(fmaxf(alpha[0], alpha[1]), fmaxf(alpha[2], alpha[3]));
        float e0 = __expf(alpha[0] - m), e1 = __expf(alpha[1] - m);
        float e2 = __expf(alpha[2] - m), e3 = __expf(alpha[3] - m);
        float inv = 1.0f / (e0 + e1 + e2 + e3);
        coefs[0] = e0 * inv; coefs[1] = e1 * inv; coefs[2] = e2 * inv; coefs[3] = e3 * inv;
    }
}

// ---------------- nnz-parallel SpMM with LDS output block ----------------
// One block per bucket (128 rows). 8 lanes per nnz, perfectly balanced,
// accumulation via ds_add_f32 with XOR bank swizzle. Fused Efin update.

template <bool INIT, bool STORE_E>
__global__ __launch_bounds__(256) void spmm_lds_kernel(
        const int2* __restrict__ pairs, const int* __restrict__ base,
        const float* __restrict__ X, float* __restrict__ Eout,
        float* __restrict__ Efin, const float* __restrict__ coefs,
        int hop, int n) {
    __shared__ float Eb[RPB * EMB];  // 16 KB
    const int t = threadIdx.x;
    const int bkt = blockIdx.x;
    #pragma unroll
    for (int i = t * 4; i < RPB * EMB; i += 256 * 4)
        *reinterpret_cast<float4*>(Eb + i) = make_float4(0.f, 0.f, 0.f, 0.f);
    __syncthreads();
    const int i0 = base[bkt], i1 = base[bkt + 1];
    const int g = t >> 3;            // 32 groups per block
    const int s4 = (t & 7) * 4;      // sub-column of EMB
    const int step = 32;

    auto body = [&](int2 p) {
        float vv = __int_as_float(p.x);
        int col = p.y & COLMASK;
        int lr = p.y >> 18;
        const float4 x = *reinterpret_cast<const float4*>(X + (size_t)col * EMB + s4);
        int sw = s4 ^ ((lr & 7) << 2);
        float* e = Eb + lr * EMB + sw;
        atomicAdd(e + 0, vv * x.x);
        atomicAdd(e + 1, vv * x.y);
        atomicAdd(e + 2, vv * x.z);
        atomicAdd(e + 3, vv * x.w);
    };

    int i = i0 + g;
    for (; i + 3 * step < i1; i += 4 * step) {
        int2 p0 = pairs[i];
        int2 p1 = pairs[i + step];
        int2 p2 = pairs[i + 2 * step];
        int2 p3 = pairs[i + 3 * step];
        body(p0); body(p1); body(p2); body(p3);
    }
    for (; i < i1; i += step) body(pairs[i]);
    __syncthreads();

    // epilogue: coalesced write-out + fused weighted accumulation
    const int row0 = bkt << BSHIFT;
    const float a = coefs[hop];
    #pragma unroll
    for (int idx = t; idx < RPB * 8; idx += 256) {
        int lr = idx >> 3;
        int sub4 = (idx & 7) * 4;
        int row = row0 + lr;
        if (row >= n) continue;
        int sw = sub4 ^ ((lr & 7) << 2);
        float4 e = *reinterpret_cast<const float4*>(Eb + lr * EMB + sw);
        size_t o = (size_t)row * EMB + sub4;
        if (STORE_E)
            *reinterpret_cast<float4*>(Eout + o) = e;
        if (INIT) {
            *reinterpret_cast<float4*>(Efin + o) =
                make_float4(a * e.x, a * e.y, a * e.z, a * e.w);
        } else {
            float4 f = *reinterpret_cast<const float4*>(Efin + o);
            f.x += a * e.x; f.y += a * e.y; f.z += a * e.z; f.w += a * e.w;
            *reinterpret_cast<float4*>(Efin + o) = f;
        }
    }
}

// ---------------- atomic fallback (if ws too small / n too big) ----------------

__global__ void spmm_atomic_kernel(const float* __restrict__ vals, const int* __restrict__ rows,
                                   const int* __restrict__ cols, int nnz,
                                   const float* __restrict__ X, float* __restrict__ Eout) {
    long long stride = (long long)gridDim.x * blockDim.x;
    long long total = (long long)nnz * 8;
    for (long long t = (long long)blockIdx.x * blockDim.x + threadIdx.x; t < total; t += stride) {
        int i = (int)(t >> 3);
        int sub = ((int)t & 7) * 4;
        float v = vals[i];
        const float4 x = *reinterpret_cast<const float4*>(X + (long long)cols[i] * EMB + sub);
        float* o = Eout + (long long)rows[i] * EMB + sub;
        atomicAdd(o + 0, v * x.x);
        atomicAdd(o + 1, v * x.y);
        atomicAdd(o + 2, v * x.z);
        atomicAdd(o + 3, v * x.w);
    }
}

template <bool INIT>
__global__ void axpy_kernel(const float* __restrict__ E, float* __restrict__ Efin,
                            const float* __restrict__ coefs, int hop, int total4) {
    int i = blockIdx.x * blockDim.x + threadIdx.x;
    if (i >= total4) return;
    float a = coefs[hop];
    float4 e = reinterpret_cast<const float4*>(E)[i];
    if (INIT) {
        reinterpret_cast<float4*>(Efin)[i] = make_float4(a * e.x, a * e.y, a * e.z, a * e.w);
    } else {
        float4 f = reinterpret_cast<float4*>(Efin)[i];
        f.x += a * e.x; f.y += a * e.y; f.z += a * e.z; f.w += a * e.w;
        reinterpret_cast<float4*>(Efin)[i] = f;
    }
}

// ---------------- launch ----------------

extern "C" void kernel_launch(void* const* d_in, const int* in_sizes, int n_in,
                              void* d_out, int out_size, void* d_ws, size_t ws_size,
                              hipStream_t stream) {
    const float* A_vals = (const float*)d_in[0];
    const float* W0     = (const float*)d_in[1];
    const float* alpha  = (const float*)d_in[2];
    const int*   A_rows = (const int*)d_in[3];
    const int*   A_cols = (const int*)d_in[4];
    const int nnz = in_sizes[0];
    const int n   = in_sizes[1] / EMB;
    float* Efin = (float*)d_out;

    char* ws = (char*)d_ws;
    size_t off = 0;
    auto alloc = [&](size_t bytes) -> void* {
        void* p = (void*)(ws + off);
        off += (bytes + 255) & ~(size_t)255;
        return p;
    };

    float* Ebuf0 = (float*)alloc((size_t)n * EMB * 4);
    float* Ebuf1 = (float*)alloc((size_t)n * EMB * 4);
    float* coefs = (float*)alloc(4 * sizeof(float));
    int*   bhist  = (int*)alloc((size_t)NBP * 4);
    int*   base   = (int*)alloc((size_t)(NBP + 1) * 4);
    int*   cursor = (int*)alloc((size_t)NBP * 4);
    int2*  pairs  = (int2*)alloc((size_t)nnz * 8);
    size_t off_csr = off;

    const int nb = (n + RPB - 1) >> BSHIFT;
    const bool use_csr = (ws_size >= off_csr) && (nb <= NBP) && (n <= COLMASK + 1);

    softmax4_kernel<<<1, 64, 0, stream>>>(alpha, coefs);

    if (use_csr) {
        hipMemsetAsync(bhist, 0, (size_t)NBP * 4, stream);
        bucket_hist_kernel<<<256, 512, 0, stream>>>(A_rows, nnz, bhist, nb);
        bucket_scan_kernel<<<1, 512, 0, stream>>>(bhist, nb, nnz, base, cursor);
        partition_kernel<<<(nnz + TILE - 1) / TILE, PT_THREADS, 0, stream>>>(
            A_vals, A_rows, A_cols, nnz, cursor, pairs);

        spmm_lds_kernel<true,  true ><<<nb, 256, 0, stream>>>(pairs, base, W0,    Ebuf0, Efin, coefs, 0, n);
        spmm_lds_kernel<false, true ><<<nb, 256, 0, stream>>>(pairs, base, Ebuf0, Ebuf1, Efin, coefs, 1, n);
        spmm_lds_kernel<false, true ><<<nb, 256, 0, stream>>>(pairs, base, Ebuf1, Ebuf0, Efin, coefs, 2, n);
        spmm_lds_kernel<false, false><<<nb, 256, 0, stream>>>(pairs, base, Ebuf0, Ebuf1, Efin, coefs, 3, n);
    } else {
        const float* X = W0;
        float* bufs[2] = {Ebuf0, Ebuf1};
        int total4 = n * EMB / 4;
        int ablocks = (total4 + 255) / 256;
        for (int hop = 0; hop < 4; ++hop) {
            float* Eo = bufs[hop & 1];
            hipMemsetAsync(Eo, 0, (size_t)n * EMB * 4, stream);
            spmm_atomic_kernel<<<2048, 256, 0, stream>>>(A_vals, A_rows, A_cols, nnz, X, Eo);
            if (hop == 0)
                axpy_kernel<true ><<<ablocks, 256, 0, stream>>>(Eo, Efin, coefs, hop, total4);
            else
                axpy_kernel<false><<<ablocks, 256, 0, stream>>>(Eo, Efin, coefs, hop, total4);
            X = Eo;
        }
    }
}

// Round 5
// 477.096 us; speedup vs baseline: 5.3541x; 5.3541x over previous
//
#include <hip/hip_runtime.h>

#define EMB 32
#define SCAN_CHUNK 1024
#define BSHIFT 10
#define ROWS_PER_BUCKET 1024
#define TILE 4096
#define PT_THREADS 256
#define PT_ITEMS 16
#define SP_THREADS 1024

// ---------------- CSR build: two-phase counting sort (R2, unchanged) ----------------

__global__ void bucket_hist_kernel(const int* __restrict__ rows, int nnz,
                                   int* __restrict__ bhist, int nb) {
    __shared__ int h[256];
    int t = threadIdx.x;
    h[t] = 0;
    __syncthreads();
    int stride = gridDim.x * blockDim.x;
    for (int i = blockIdx.x * blockDim.x + t; i < nnz; i += stride)
        atomicAdd(&h[rows[i] >> BSHIFT], 1);
    __syncthreads();
    if (t < nb && h[t] > 0) atomicAdd(&bhist[t], h[t]);
}

__global__ void bucket_scan_kernel(const int* __restrict__ bhist, int nb, int nnz,
                                   int* __restrict__ base, int* __restrict__ cursor) {
    __shared__ int lds[256];
    int t = threadIdx.x;
    int s = (t < nb) ? bhist[t] : 0;
    lds[t] = s;
    __syncthreads();
    for (int off = 1; off < 256; off <<= 1) {
        int add = (t >= off) ? lds[t - off] : 0;
        __syncthreads();
        lds[t] += add;
        __syncthreads();
    }
    if (t < nb) {
        int e = lds[t] - s;
        base[t] = e;
        cursor[t] = e;
    }
    if (t == 0) base[nb] = nnz;
}

__global__ __launch_bounds__(PT_THREADS) void partition_kernel(
        const float* __restrict__ vals, const int* __restrict__ rows,
        const int* __restrict__ cols, int nnz, int* __restrict__ cursor,
        int2* __restrict__ pairs_stage, int* __restrict__ rows_stage) {
    __shared__ int h[256], sc[256], delta[256], cur[256];
    __shared__ float s_val[TILE];
    __shared__ int s_col[TILE], s_row[TILE];
    const int t = threadIdx.x;
    const int tile_start = blockIdx.x * TILE;
    const int tile_cnt = min(TILE, nnz - tile_start);
    h[t] = 0;
    __syncthreads();
    float v[PT_ITEMS];
    int c[PT_ITEMS], r[PT_ITEMS], b[PT_ITEMS];
    #pragma unroll
    for (int k = 0; k < PT_ITEMS; ++k) {
        int i = tile_start + t + k * PT_THREADS;
        if (i < nnz) {
            v[k] = vals[i];
            c[k] = cols[i];
            r[k] = rows[i];
            b[k] = r[k] >> BSHIFT;
            atomicAdd(&h[b[k]], 1);
        } else {
            b[k] = -1;
        }
    }
    __syncthreads();
    int own = h[t];
    sc[t] = own;
    __syncthreads();
    for (int off = 1; off < 256; off <<= 1) {
        int add = (t >= off) ? sc[t - off] : 0;
        __syncthreads();
        sc[t] += add;
        __syncthreads();
    }
    int excl = sc[t] - own;
    if (own > 0) {
        int rsv = atomicAdd(&cursor[t], own);
        delta[t] = rsv - excl;
    }
    cur[t] = excl;
    __syncthreads();
    #pragma unroll
    for (int k = 0; k < PT_ITEMS; ++k) {
        if (b[k] >= 0) {
            int rank = atomicAdd(&cur[b[k]], 1);
            s_val[rank] = v[k];
            s_col[rank] = c[k];
            s_row[rank] = r[k];
        }
    }
    __syncthreads();
    for (int i = t; i < tile_cnt; i += PT_THREADS) {
        int rw = s_row[i];
        int bb = rw >> BSHIFT;
        int gpos = delta[bb] + i;
        pairs_stage[gpos] = make_int2(__float_as_int(s_val[i]), s_col[i]);
        rows_stage[gpos] = rw;
    }
}

__global__ __launch_bounds__(SP_THREADS) void bucket_sort_kernel(
        const int2* __restrict__ pairs_stage, const int* __restrict__ rows_stage,
        const int* __restrict__ base, int n, int nnz,
        int* __restrict__ row_ptr, int2* __restrict__ pairs) {
    __shared__ int rh[ROWS_PER_BUCKET];
    __shared__ int rc[ROWS_PER_BUCKET];
    const int bkt = blockIdx.x;
    const int t = threadIdx.x;
    const int row0 = bkt << BSHIFT;
    const int nrows = min(ROWS_PER_BUCKET, n - row0);
    const int i0 = base[bkt], i1 = base[bkt + 1];
    rh[t] = 0;
    __syncthreads();
    for (int i = i0 + t; i < i1; i += SP_THREADS)
        atomicAdd(&rh[rows_stage[i] - row0], 1);
    __syncthreads();
    int own = rh[t];
    for (int off = 1; off < SP_THREADS; off <<= 1) {
        int add = (t >= off) ? rh[t - off] : 0;
        __syncthreads();
        rh[t] += add;
        __syncthreads();
    }
    int excl = rh[t] - own;
    if (t < nrows) row_ptr[row0 + t] = i0 + excl;
    rc[t] = excl;
    if (bkt == 0 && t == 0) row_ptr[n] = nnz;
    __syncthreads();
    for (int i = i0 + t; i < i1; i += SP_THREADS) {
        int2 p = pairs_stage[i];
        int r = rows_stage[i] - row0;
        int pos = i0 + atomicAdd(&rc[r], 1);
        pairs[pos] = p;
    }
}

// ---------------- misc ----------------

__global__ void softmax4_kernel(const float* __restrict__ alpha, float* __restrict__ coefs) {
    if (threadIdx.x == 0 && blockIdx.x == 0) {
        float m = fmaxf(fmaxf(alpha[0], alpha[1]), fmaxf(alpha[2], alpha[3]));
        float e0 = __expf(alpha[0] - m), e1 = __expf(alpha[1] - m);
        float e2 = __expf(alpha[2] - m), e3 = __expf(alpha[3] - m);
        float inv = 1.0f / (e0 + e1 + e2 + e3);
        coefs[0] = e0 * inv; coefs[1] = e1 * inv; coefs[2] = e2 * inv; coefs[3] = e3 * inv;
    }
}

// ---------------- CSR SpMM, 4x-unrolled for MLP ----------------
// 8 lanes per row, float4 of EMB per lane. Pairs contiguous per row ->
// two aligned int4 loads cover 4 nnz; 4 independent X gathers in flight.

template <bool INIT, bool STORE_E>
__global__ __launch_bounds__(256) void spmm_kernel(
        const int* __restrict__ row_ptr, const int2* __restrict__ pairs,
        const float* __restrict__ X, float* __restrict__ Eout,
        float* __restrict__ Efin, const float* __restrict__ coefs,
        int hop, int n) {
    int tid = blockIdx.x * blockDim.x + threadIdx.x;
    int row = tid >> 3;
    if (row >= n) return;
    const int sub = (tid & 7) * 4;
    int j = row_ptr[row];
    const int j1 = row_ptr[row + 1];
    float ax = 0.f, ay = 0.f, az = 0.f, aw = 0.f;

    // peel to even j so int4 loads are 16B-aligned (pairs base is 256B-aligned)
    if ((j & 1) && j < j1) {
        int2 p = pairs[j];
        float v = __int_as_float(p.x);
        const float4 x = *reinterpret_cast<const float4*>(X + (size_t)p.y * EMB + sub);
        ax = fmaf(v, x.x, ax); ay = fmaf(v, x.y, ay);
        az = fmaf(v, x.z, az); aw = fmaf(v, x.w, aw);
        ++j;
    }
    for (; j + 4 <= j1; j += 4) {
        const int4 pa = *reinterpret_cast<const int4*>(pairs + j);       // nnz j, j+1
        const int4 pb = *reinterpret_cast<const int4*>(pairs + j + 2);   // nnz j+2, j+3
        const float4 x0 = *reinterpret_cast<const float4*>(X + (size_t)pa.y * EMB + sub);
        const float4 x1 = *reinterpret_cast<const float4*>(X + (size_t)pa.w * EMB + sub);
        const float4 x2 = *reinterpret_cast<const float4*>(X + (size_t)pb.y * EMB + sub);
        const float4 x3 = *reinterpret_cast<const float4*>(X + (size_t)pb.w * EMB + sub);
        const float v0 = __int_as_float(pa.x), v1 = __int_as_float(pa.z);
        const float v2 = __int_as_float(pb.x), v3 = __int_as_float(pb.z);
        ax = fmaf(v0, x0.x, ax); ay = fmaf(v0, x0.y, ay);
        az = fmaf(v0, x0.z, az); aw = fmaf(v0, x0.w, aw);
        ax = fmaf(v1, x1.x, ax); ay = fmaf(v1, x1.y, ay);
        az = fmaf(v1, x1.z, az); aw = fmaf(v1, x1.w, aw);
        ax = fmaf(v2, x2.x, ax); ay = fmaf(v2, x2.y, ay);
        az = fmaf(v2, x2.z, az); aw = fmaf(v2, x2.w, aw);
        ax = fmaf(v3, x3.x, ax); ay = fmaf(v3, x3.y, ay);
        az = fmaf(v3, x3.z, az); aw = fmaf(v3, x3.w, aw);
    }
    for (; j < j1; ++j) {
        int2 p = pairs[j];
        float v = __int_as_float(p.x);
        const float4 x = *reinterpret_cast<const float4*>(X + (size_t)p.y * EMB + sub);
        ax = fmaf(v, x.x, ax); ay = fmaf(v, x.y, ay);
        az = fmaf(v, x.z, az); aw = fmaf(v, x.w, aw);
    }

    const size_t o = (size_t)row * EMB + sub;
    if (STORE_E)
        *reinterpret_cast<float4*>(Eout + o) = make_float4(ax, ay, az, aw);
    const float a = coefs[hop];
    if (INIT) {
        *reinterpret_cast<float4*>(Efin + o) = make_float4(a * ax, a * ay, a * az, a * aw);
    } else {
        float4 f = *reinterpret_cast<const float4*>(Efin + o);
        f.x += a * ax; f.y += a * ay; f.z += a * az; f.w += a * aw;
        *reinterpret_cast<float4*>(Efin + o) = f;
    }
}

// ---------------- atomic fallback (if ws too small) ----------------

__global__ void spmm_atomic_kernel(const float* __restrict__ vals, const int* __restrict__ rows,
                                   const int* __restrict__ cols, int nnz,
                                   const float* __restrict__ X, float* __restrict__ Eout) {
    long long stride = (long long)gridDim.x * blockDim.x;
    long long total = (long long)nnz * 8;
    for (long long t = (long long)blockIdx.x * blockDim.x + threadIdx.x; t < total; t += stride) {
        int i = (int)(t >> 3);
        int sub = ((int)t & 7) * 4;
        float v = vals[i];
        const float4 x = *reinterpret_cast<const float4*>(X + (long long)cols[i] * EMB + sub);
        float* o = Eout + (long long)rows[i] * EMB + sub;
        atomicAdd(o + 0, v * x.x);
        atomicAdd(o + 1, v * x.y);
        atomicAdd(o + 2, v * x.z);
        atomicAdd(o + 3, v * x.w);
    }
}

template <bool INIT>
__global__ void axpy_kernel(const float* __restrict__ E, float* __restrict__ Efin,
                            const float* __restrict__ coefs, int hop, int total4) {
    int i = blockIdx.x * blockDim.x + threadIdx.x;
    if (i >= total4) return;
    float a = coefs[hop];
    float4 e = reinterpret_cast<const float4*>(E)[i];
    if (INIT) {
        reinterpret_cast<float4*>(Efin)[i] = make_float4(a * e.x, a * e.y, a * e.z, a * e.w);
    } else {
        float4 f = reinterpret_cast<float4*>(Efin)[i];
        f.x += a * e.x; f.y += a * e.y; f.z += a * e.z; f.w += a * e.w;
        reinterpret_cast<float4*>(Efin)[i] = f;
    }
}

// ---------------- launch ----------------

extern "C" void kernel_launch(void* const* d_in, const int* in_sizes, int n_in,
                              void* d_out, int out_size, void* d_ws, size_t ws_size,
                              hipStream_t stream) {
    const float* A_vals = (const float*)d_in[0];
    const float* W0     = (const float*)d_in[1];
    const float* alpha  = (const float*)d_in[2];
    const int*   A_rows = (const int*)d_in[3];
    const int*   A_cols = (const int*)d_in[4];
    const int nnz = in_sizes[0];
    const int n   = in_sizes[1] / EMB;
    float* Efin = (float*)d_out;

    char* ws = (char*)d_ws;
    size_t off = 0;
    auto alloc = [&](size_t bytes) -> void* {
        void* p = (void*)(ws + off);
        off += (bytes + 255) & ~(size_t)255;
        return p;
    };

    float* Ebuf0 = (float*)alloc((size_t)n * EMB * 4);
    float* Ebuf1 = (float*)alloc((size_t)n * EMB * 4);
    float* coefs = (float*)alloc(4 * sizeof(float));
    int*  row_ptr = (int*)alloc((size_t)(n + 1) * 4);
    int*  bhist   = (int*)alloc(256 * 4);
    int*  base    = (int*)alloc(257 * 4);
    int*  cursor  = (int*)alloc(256 * 4);
    int2* pairs   = (int2*)alloc((size_t)nnz * 8);
    size_t off_csr = off;

    int2* pairs_stage = (int2*)Ebuf0;
    int*  rows_stage  = (int*)Ebuf1;

    const int nb = (n + ROWS_PER_BUCKET - 1) >> BSHIFT;
    const bool use_csr = (ws_size >= off_csr) && (nb <= 256) &&
                         ((size_t)nnz * 8 <= (size_t)n * EMB * 4);

    softmax4_kernel<<<1, 64, 0, stream>>>(alpha, coefs);

    if (use_csr) {
        hipMemsetAsync(bhist, 0, 256 * 4, stream);
        bucket_hist_kernel<<<1024, 256, 0, stream>>>(A_rows, nnz, bhist, nb);
        bucket_scan_kernel<<<1, 256, 0, stream>>>(bhist, nb, nnz, base, cursor);
        partition_kernel<<<(nnz + TILE - 1) / TILE, PT_THREADS, 0, stream>>>(
            A_vals, A_rows, A_cols, nnz, cursor, pairs_stage, rows_stage);
        bucket_sort_kernel<<<nb, SP_THREADS, 0, stream>>>(
            pairs_stage, rows_stage, base, n, nnz, row_ptr, pairs);

        int blocks = (n * 8 + 255) / 256;
        spmm_kernel<true,  true ><<<blocks, 256, 0, stream>>>(row_ptr, pairs, W0,    Ebuf0, Efin, coefs, 0, n);
        spmm_kernel<false, true ><<<blocks, 256, 0, stream>>>(row_ptr, pairs, Ebuf0, Ebuf1, Efin, coefs, 1, n);
        spmm_kernel<false, true ><<<blocks, 256, 0, stream>>>(row_ptr, pairs, Ebuf1, Ebuf0, Efin, coefs, 2, n);
        spmm_kernel<false, false><<<blocks, 256, 0, stream>>>(row_ptr, pairs, Ebuf0, Ebuf1, Efin, coefs, 3, n);
    } else {
        const float* X = W0;
        float* bufs[2] = {Ebuf0, Ebuf1};
        int total4 = n * EMB / 4;
        int ablocks = (total4 + 255) / 256;
        for (int hop = 0; hop < 4; ++hop) {
            float* Eo = bufs[hop & 1];
            hipMemsetAsync(Eo, 0, (size_t)n * EMB * 4, stream);
            spmm_atomic_kernel<<<2048, 256, 0, stream>>>(A_vals, A_rows, A_cols, nnz, X, Eo);
            if (hop == 0)
                axpy_kernel<true ><<<ablocks, 256, 0, stream>>>(Eo, Efin, coefs, hop, total4);
            else
                axpy_kernel<false><<<ablocks, 256, 0, stream>>>(Eo, Efin, coefs, hop, total4);
            X = Eo;
        }
    }
}

// Round 6
// 471.737 us; speedup vs baseline: 5.4149x; 1.0114x over previous
//
#include <hip/hip_runtime.h>

#define EMB 32
#define BSHIFT 10
#define RPB 1024           // rows per bucket
#define NB 256             // max buckets
#define TILE 4096
#define PT_THREADS 256
#define PT_ITEMS 16
#define SP_THREADS 1024
#define COLMASK 0x3FFFF    // 18 bits col (n <= 262144); lrow in bits 18..27

// ---------------- CSR build ----------------

__global__ void bucket_hist_kernel(const int* __restrict__ rows, int nnz,
                                   int* __restrict__ bhist, int nb) {
    __shared__ int h[NB];
    int t = threadIdx.x;
    h[t] = 0;
    __syncthreads();
    int stride = gridDim.x * blockDim.x;
    for (int i = blockIdx.x * blockDim.x + t; i < nnz; i += stride)
        atomicAdd(&h[rows[i] >> BSHIFT], 1);
    __syncthreads();
    if (t < nb && h[t] > 0) atomicAdd(&bhist[t], h[t]);
}

// Tile-wise partition into bucket-grouped (val, col|lrow<<18) + lrow sidecar.
// Global bucket bases computed by a local scan of bhist (no scan dispatch);
// cursor[] holds relative offsets (memset-0 initialized).
__global__ __launch_bounds__(PT_THREADS) void partition_kernel(
        const float* __restrict__ vals, const int* __restrict__ rows,
        const int* __restrict__ cols, int nnz,
        const int* __restrict__ bhist, int* __restrict__ cursor,
        int2* __restrict__ pairs_stage, unsigned short* __restrict__ lrow_stage) {
    __shared__ int locbase[NB];
    __shared__ int h[NB];
    __shared__ int sc[NB];
    __shared__ int delta[NB];
    __shared__ float s_val[TILE];
    __shared__ int s_pack[TILE];
    __shared__ unsigned short s_bkt[TILE];
    const int t = threadIdx.x;
    const int tile_start = blockIdx.x * TILE;
    const int tile_cnt = min(TILE, nnz - tile_start);

    // local exclusive scan of bhist -> per-bucket global base (in reg eb)
    const int ownb = bhist[t];
    locbase[t] = ownb;
    h[t] = 0;
    __syncthreads();
    for (int off = 1; off < NB; off <<= 1) {
        int add = (t >= off) ? locbase[t - off] : 0;
        __syncthreads();
        locbase[t] += add;
        __syncthreads();
    }
    const int eb = locbase[t] - ownb;   // exclusive base of bucket t

    float v[PT_ITEMS];
    int pk[PT_ITEMS], b[PT_ITEMS];
    #pragma unroll
    for (int k = 0; k < PT_ITEMS; ++k) {
        int i = tile_start + t + k * PT_THREADS;
        if (i < nnz) {
            int r = rows[i];
            v[k] = vals[i];
            pk[k] = cols[i] | ((r & (RPB - 1)) << 18);
            b[k] = r >> BSHIFT;
            atomicAdd(&h[b[k]], 1);
        } else {
            b[k] = -1;
        }
    }
    __syncthreads();
    const int own = h[t];
    sc[t] = own;
    __syncthreads();
    for (int off = 1; off < NB; off <<= 1) {
        int add = (t >= off) ? sc[t - off] : 0;
        __syncthreads();
        sc[t] += add;
        __syncthreads();
    }
    const int excl = sc[t] - own;
    if (own > 0) {
        int old = atomicAdd(&cursor[t], own);   // relative reservation
        delta[t] = (eb + old) - excl;
    }
    h[t] = excl;                                // rank cursor
    __syncthreads();
    #pragma unroll
    for (int k = 0; k < PT_ITEMS; ++k) {
        if (b[k] >= 0) {
            int rank = atomicAdd(&h[b[k]], 1);
            s_val[rank] = v[k];
            s_pack[rank] = pk[k];
            s_bkt[rank] = (unsigned short)b[k];
        }
    }
    __syncthreads();
    for (int i = t; i < tile_cnt; i += PT_THREADS) {
        int bb = s_bkt[i];
        int gpos = delta[bb] + i;
        int pk_i = s_pack[i];
        pairs_stage[gpos] = make_int2(__float_as_int(s_val[i]), pk_i);
        lrow_stage[gpos] = (unsigned short)(((unsigned)pk_i) >> 18);
    }
}

// Per-bucket counting sort -> row_ptr + final CSR pairs (col stripped of lrow).
// Bucket base recomputed by local scan of bhist.
__global__ __launch_bounds__(SP_THREADS) void bucket_sort_kernel(
        const int2* __restrict__ pairs_stage, const unsigned short* __restrict__ lrow_stage,
        const int* __restrict__ bhist, int n, int nnz,
        int* __restrict__ row_ptr, int2* __restrict__ pairs) {
    __shared__ int rh[RPB];
    __shared__ int rc[RPB];
    const int bkt = blockIdx.x;
    const int t = threadIdx.x;

    // inclusive scan of bhist in rh[0..NB)
    if (t < NB) rh[t] = bhist[t];
    __syncthreads();
    for (int off = 1; off < NB; off <<= 1) {
        int add = 0;
        if (t < NB && t >= off) add = rh[t - off];
        __syncthreads();
        if (t < NB) rh[t] += add;
        __syncthreads();
    }
    const int i0 = (bkt > 0) ? rh[bkt - 1] : 0;
    const int i1 = rh[bkt];
    __syncthreads();

    const int row0 = bkt << BSHIFT;
    const int nrows = min(RPB, n - row0);
    rh[t] = 0;
    __syncthreads();
    for (int i = i0 + t; i < i1; i += SP_THREADS)
        atomicAdd(&rh[lrow_stage[i]], 1);
    __syncthreads();
    const int own = rh[t];
    for (int off = 1; off < SP_THREADS; off <<= 1) {
        int add = (t >= off) ? rh[t - off] : 0;
        __syncthreads();
        rh[t] += add;
        __syncthreads();
    }
    const int excl = rh[t] - own;
    if (t < nrows) row_ptr[row0 + t] = i0 + excl;
    rc[t] = excl;
    if (bkt == 0 && t == 0) row_ptr[n] = nnz;
    __syncthreads();
    for (int i = i0 + t; i < i1; i += SP_THREADS) {
        int2 p = pairs_stage[i];
        int r = lrow_stage[i];
        int pos = i0 + atomicAdd(&rc[r], 1);
        pairs[pos] = make_int2(p.x, p.y & COLMASK);
    }
}

// ---------------- misc ----------------

__global__ void softmax4_kernel(const float* __restrict__ alpha, float* __restrict__ coefs) {
    if (threadIdx.x == 0 && blockIdx.x == 0) {
        float m = fmaxf(fmaxf(alpha[0], alpha[1]), fmaxf(alpha[2], alpha[3]));
        float e0 = __expf(alpha[0] - m), e1 = __expf(alpha[1] - m);
        float e2 = __expf(alpha[2] - m), e3 = __expf(alpha[3] - m);
        float inv = 1.0f / (e0 + e1 + e2 + e3);
        coefs[0] = e0 * inv; coefs[1] = e1 * inv; coefs[2] = e2 * inv; coefs[3] = e3 * inv;
    }
}

// ---------------- CSR SpMM, 4x-unrolled (byte-identical to R5 control) ----------------

template <bool INIT, bool STORE_E>
__global__ __launch_bounds__(256) void spmm_kernel(
        const int* __restrict__ row_ptr, const int2* __restrict__ pairs,
        const float* __restrict__ X, float* __restrict__ Eout,
        float* __restrict__ Efin, const float* __restrict__ coefs,
        int hop, int n) {
    int tid = blockIdx.x * blockDim.x + threadIdx.x;
    int row = tid >> 3;
    if (row >= n) return;
    const int sub = (tid & 7) * 4;
    int j = row_ptr[row];
    const int j1 = row_ptr[row + 1];
    float ax = 0.f, ay = 0.f, az = 0.f, aw = 0.f;

    if ((j & 1) && j < j1) {
        int2 p = pairs[j];
        float v = __int_as_float(p.x);
        const float4 x = *reinterpret_cast<const float4*>(X + (size_t)p.y * EMB + sub);
        ax = fmaf(v, x.x, ax); ay = fmaf(v, x.y, ay);
        az = fmaf(v, x.z, az); aw = fmaf(v, x.w, aw);
        ++j;
    }
    for (; j + 4 <= j1; j += 4) {
        const int4 pa = *reinterpret_cast<const int4*>(pairs + j);
        const int4 pb = *reinterpret_cast<const int4*>(pairs + j + 2);
        const float4 x0 = *reinterpret_cast<const float4*>(X + (size_t)pa.y * EMB + sub);
        const float4 x1 = *reinterpret_cast<const float4*>(X + (size_t)pa.w * EMB + sub);
        const float4 x2 = *reinterpret_cast<const float4*>(X + (size_t)pb.y * EMB + sub);
        const float4 x3 = *reinterpret_cast<const float4*>(X + (size_t)pb.w * EMB + sub);
        const float v0 = __int_as_float(pa.x), v1 = __int_as_float(pa.z);
        const float v2 = __int_as_float(pb.x), v3 = __int_as_float(pb.z);
        ax = fmaf(v0, x0.x, ax); ay = fmaf(v0, x0.y, ay);
        az = fmaf(v0, x0.z, az); aw = fmaf(v0, x0.w, aw);
        ax = fmaf(v1, x1.x, ax); ay = fmaf(v1, x1.y, ay);
        az = fmaf(v1, x1.z, az); aw = fmaf(v1, x1.w, aw);
        ax = fmaf(v2, x2.x, ax); ay = fmaf(v2, x2.y, ay);
        az = fmaf(v2, x2.z, az); aw = fmaf(v2, x2.w, aw);
        ax = fmaf(v3, x3.x, ax); ay = fmaf(v3, x3.y, ay);
        az = fmaf(v3, x3.z, az); aw = fmaf(v3, x3.w, aw);
    }
    for (; j < j1; ++j) {
        int2 p = pairs[j];
        float v = __int_as_float(p.x);
        const float4 x = *reinterpret_cast<const float4*>(X + (size_t)p.y * EMB + sub);
        ax = fmaf(v, x.x, ax); ay = fmaf(v, x.y, ay);
        az = fmaf(v, x.z, az); aw = fmaf(v, x.w, aw);
    }

    const size_t o = (size_t)row * EMB + sub;
    if (STORE_E)
        *reinterpret_cast<float4*>(Eout + o) = make_float4(ax, ay, az, aw);
    const float a = coefs[hop];
    if (INIT) {
        *reinterpret_cast<float4*>(Efin + o) = make_float4(a * ax, a * ay, a * az, a * aw);
    } else {
        float4 f = *reinterpret_cast<const float4*>(Efin + o);
        f.x += a * ax; f.y += a * ay; f.z += a * az; f.w += a * aw;
        *reinterpret_cast<float4*>(Efin + o) = f;
    }
}

// ---------------- atomic fallback (if ws too small / n too big) ----------------

__global__ void spmm_atomic_kernel(const float* __restrict__ vals, const int* __restrict__ rows,
                                   const int* __restrict__ cols, int nnz,
                                   const float* __restrict__ X, float* __restrict__ Eout) {
    long long stride = (long long)gridDim.x * blockDim.x;
    long long total = (long long)nnz * 8;
    for (long long t = (long long)blockIdx.x * blockDim.x + threadIdx.x; t < total; t += stride) {
        int i = (int)(t >> 3);
        int sub = ((int)t & 7) * 4;
        float v = vals[i];
        const float4 x = *reinterpret_cast<const float4*>(X + (long long)cols[i] * EMB + sub);
        float* o = Eout + (long long)rows[i] * EMB + sub;
        atomicAdd(o + 0, v * x.x);
        atomicAdd(o + 1, v * x.y);
        atomicAdd(o + 2, v * x.z);
        atomicAdd(o + 3, v * x.w);
    }
}

template <bool INIT>
__global__ void axpy_kernel(const float* __restrict__ E, float* __restrict__ Efin,
                            const float* __restrict__ coefs, int hop, int total4) {
    int i = blockIdx.x * blockDim.x + threadIdx.x;
    if (i >= total4) return;
    float a = coefs[hop];
    float4 e = reinterpret_cast<const float4*>(E)[i];
    if (INIT) {
        reinterpret_cast<float4*>(Efin)[i] = make_float4(a * e.x, a * e.y, a * e.z, a * e.w);
    } else {
        float4 f = reinterpret_cast<float4*>(Efin)[i];
        f.x += a * e.x; f.y += a * e.y; f.z += a * e.z; f.w += a * e.w;
        reinterpret_cast<float4*>(Efin)[i] = f;
    }
}

// ---------------- launch ----------------

extern "C" void kernel_launch(void* const* d_in, const int* in_sizes, int n_in,
                              void* d_out, int out_size, void* d_ws, size_t ws_size,
                              hipStream_t stream) {
    const float* A_vals = (const float*)d_in[0];
    const float* W0     = (const float*)d_in[1];
    const float* alpha  = (const float*)d_in[2];
    const int*   A_rows = (const int*)d_in[3];
    const int*   A_cols = (const int*)d_in[4];
    const int nnz = in_sizes[0];
    const int n   = in_sizes[1] / EMB;
    float* Efin = (float*)d_out;

    char* ws = (char*)d_ws;
    size_t off = 0;
    auto alloc = [&](size_t bytes) -> void* {
        void* p = (void*)(ws + off);
        off += (bytes + 255) & ~(size_t)255;
        return p;
    };

    float* Ebuf0 = (float*)alloc((size_t)n * EMB * 4);
    float* Ebuf1 = (float*)alloc((size_t)n * EMB * 4);
    float* coefs = (float*)alloc(4 * sizeof(float));
    int*  row_ptr = (int*)alloc((size_t)(n + 1) * 4);
    int*  bhist   = (int*)alloc(NB * 4);       // contiguous with cursor:
    int*  cursor  = (int*)alloc(NB * 4);       // one 2 KB memset covers both
    int2* pairs   = (int2*)alloc((size_t)nnz * 8);
    size_t off_csr = off;

    int2* pairs_stage = (int2*)Ebuf0;                     // nnz*8 B
    unsigned short* lrow_stage = (unsigned short*)Ebuf1;  // nnz*2 B

    const int nb = (n + RPB - 1) >> BSHIFT;
    const bool use_csr = (ws_size >= off_csr) && (nb <= NB) && (n <= COLMASK + 1) &&
                         ((size_t)nnz * 8 <= (size_t)n * EMB * 4);

    softmax4_kernel<<<1, 64, 0, stream>>>(alpha, coefs);

    if (use_csr) {
        hipMemsetAsync(bhist, 0, 2 * NB * 4, stream);   // bhist + cursor
        bucket_hist_kernel<<<1024, 256, 0, stream>>>(A_rows, nnz, bhist, nb);
        partition_kernel<<<(nnz + TILE - 1) / TILE, PT_THREADS, 0, stream>>>(
            A_vals, A_rows, A_cols, nnz, bhist, cursor, pairs_stage, lrow_stage);
        bucket_sort_kernel<<<nb, SP_THREADS, 0, stream>>>(
            pairs_stage, lrow_stage, bhist, n, nnz, row_ptr, pairs);

        int blocks = (n * 8 + 255) / 256;
        spmm_kernel<true,  true ><<<blocks, 256, 0, stream>>>(row_ptr, pairs, W0,    Ebuf0, Efin, coefs, 0, n);
        spmm_kernel<false, true ><<<blocks, 256, 0, stream>>>(row_ptr, pairs, Ebuf0, Ebuf1, Efin, coefs, 1, n);
        spmm_kernel<false, true ><<<blocks, 256, 0, stream>>>(row_ptr, pairs, Ebuf1, Ebuf0, Efin, coefs, 2, n);
        spmm_kernel<false, false><<<blocks, 256, 0, stream>>>(row_ptr, pairs, Ebuf0, Ebuf1, Efin, coefs, 3, n);
    } else {
        const float* X = W0;
        float* bufs[2] = {Ebuf0, Ebuf1};
        int total4 = n * EMB / 4;
        int ablocks = (total4 + 255) / 256;
        for (int hop = 0; hop < 4; ++hop) {
            float* Eo = bufs[hop & 1];
            hipMemsetAsync(Eo, 0, (size_t)n * EMB * 4, stream);
            spmm_atomic_kernel<<<2048, 256, 0, stream>>>(A_vals, A_rows, A_cols, nnz, X, Eo);
            if (hop == 0)
                axpy_kernel<true ><<<ablocks, 256, 0, stream>>>(Eo, Efin, coefs, hop, total4);
            else
                axpy_kernel<false><<<ablocks, 256, 0, stream>>>(Eo, Efin, coefs, hop, total4);
            X = Eo;
        }
    }
}